// Round 7
// baseline (1424.283 us; speedup 1.0000x reference)
//
#include <hip/hip_runtime.h>

#define BS 16
#define LQ 300
#define D 256
#define NH 8
#define HD 32
#define DFF 1024
#define ROWS (BS*LQ)    // 4800
#define LEN_V 8500

typedef __attribute__((ext_vector_type(8))) short short8;
typedef __attribute__((ext_vector_type(4))) float f32x4;
typedef unsigned short ushort_t;

// bf16 round-to-nearest-even (low 16 bits)
__device__ __forceinline__ uint32_t bf16r(float x)
{
    const uint32_t u = __float_as_uint(x);
    return (u + 0x7fffu + ((u >> 16) & 1u)) >> 16;
}
__device__ __forceinline__ float lof(uint32_t p) { return __uint_as_float(p << 16); }
__device__ __forceinline__ float hif(uint32_t p) { return __uint_as_float(p & 0xffff0000u); }

// ---------------------------------------------------------------------------
// MFMA GEMM, tile 64 x BN (BN = 64 or 128), BK=64, 256 thr = 4 waves.
// Wave tile 32 x BN/2; 2 x BN/32 fragments of 16x16x32. f32 A and W, cvt to
// bf16 during staging into XOR-swizzled LDS (R3-proven fragment path).
// Per-bn selects (wave-uniform):
//   A-select:  bn >= bnsplit_a -> Aalt           (merged QKV)
//   W/C-select: bn >= bnw -> W2/bias2/C2/ldc2    (merged so|aw)
//   k-concat:  A2 != null && kg >= ksplit -> A2  (gates [t|t2] fusion)
// ACT: 0=none 1=relu 2=sigmoid
// ---------------------------------------------------------------------------
template<int ACT, int BN>
__global__ __launch_bounds__(256)
void gemm_f32(const float* __restrict__ A, const float* __restrict__ Aalt,
              int bnsplit_a, int lda,
              const float* __restrict__ A2, int lda2, int ksplit,
              const float* __restrict__ W, const float* __restrict__ W2, int bnw,
              const float* __restrict__ bias, const float* __restrict__ bias2,
              float* __restrict__ C, int ldc, float* __restrict__ C2, int ldc2,
              int K)
{
    constexpr int NFR = BN / 32;          // n-fragments per wave (2 or 4)
    constexpr int BP  = BN / 32;          // B staging passes (2 or 4)
    __shared__ __align__(16) ushort_t As[64*64];
    __shared__ __align__(16) ushort_t Bs[BN*64];
    const int tid  = threadIdx.x;
    const int bm   = blockIdx.x, bn = blockIdx.y;
    const int lane = tid & 63;
    const int w    = tid >> 6;
    const int wm   = (w >> 1) * 32, wn = (w & 1) * (BN/2);
    const int fr   = lane & 15;     // fragment row/col
    const int fq   = lane >> 4;     // k-quad

    const int srow = tid >> 3;      // staging row base 0..31
    const int slot = tid & 7;       // k-slot 0..7 (8 bf16 each)

    // wave-uniform selects
    if (bn >= bnsplit_a) A = Aalt;
    const float* Wb; const float* biasb; float* Cb; int ldcb; int colbase;
    if (bn < bnw) {
        Wb = W  + (size_t)bn*BN*K;        biasb = bias;
        Cb = C;  ldcb = ldc;  colbase = bn*BN;
    } else {
        Wb = W2 + (size_t)(bn-bnw)*BN*K;  biasb = bias2;
        Cb = C2; ldcb = ldc2; colbase = (bn-bnw)*BN;
    }

    f32x4 acc[2][NFR] = {};

    for (int k0 = 0; k0 < K; k0 += 64) {
        const int kg = k0 + slot*8;
        float4 a0[2], a1[2], b0[BP], b1[BP];
#pragma unroll
        for (int pa = 0; pa < 2; ++pa) {
            const int row = srow + 32*pa;
            const float* Asrc = (A2 != nullptr && kg >= ksplit)
                ? (A2 + (size_t)(bm*64 + row)*lda2 + (kg - ksplit))
                : (A  + (size_t)(bm*64 + row)*lda  + kg);
            a0[pa] = *reinterpret_cast<const float4*>(Asrc);
            a1[pa] = *reinterpret_cast<const float4*>(Asrc + 4);
        }
#pragma unroll
        for (int pb = 0; pb < BP; ++pb) {
            const int row = srow + 32*pb;
            const float* Wsrc = Wb + (size_t)row*K + kg;
            b0[pb] = *reinterpret_cast<const float4*>(Wsrc);
            b1[pb] = *reinterpret_cast<const float4*>(Wsrc + 4);
        }
        __syncthreads();
#pragma unroll
        for (int pa = 0; pa < 2; ++pa) {
            const int row = srow + 32*pa;
            const int sl  = slot ^ (row & 7);
            uint32_t pk[4];
            pk[0] = bf16r(a0[pa].x) | (bf16r(a0[pa].y) << 16);
            pk[1] = bf16r(a0[pa].z) | (bf16r(a0[pa].w) << 16);
            pk[2] = bf16r(a1[pa].x) | (bf16r(a1[pa].y) << 16);
            pk[3] = bf16r(a1[pa].z) | (bf16r(a1[pa].w) << 16);
            *reinterpret_cast<uint4*>(&As[row*64 + sl*8]) =
                make_uint4(pk[0], pk[1], pk[2], pk[3]);
        }
#pragma unroll
        for (int pb = 0; pb < BP; ++pb) {
            const int row = srow + 32*pb;
            const int sl  = slot ^ (row & 7);
            uint32_t pk[4];
            pk[0] = bf16r(b0[pb].x) | (bf16r(b0[pb].y) << 16);
            pk[1] = bf16r(b0[pb].z) | (bf16r(b0[pb].w) << 16);
            pk[2] = bf16r(b1[pb].x) | (bf16r(b1[pb].y) << 16);
            pk[3] = bf16r(b1[pb].z) | (bf16r(b1[pb].w) << 16);
            *reinterpret_cast<uint4*>(&Bs[row*64 + sl*8]) =
                make_uint4(pk[0], pk[1], pk[2], pk[3]);
        }
        __syncthreads();
#pragma unroll
        for (int ks = 0; ks < 2; ++ks) {
            short8 af[2], bf[NFR];
#pragma unroll
            for (int fm = 0; fm < 2; ++fm) {
                const int row = wm + fm*16 + fr;
                const int sl  = (ks*4 + fq) ^ (row & 7);
                af[fm] = *reinterpret_cast<const short8*>(&As[row*64 + sl*8]);
            }
#pragma unroll
            for (int fn = 0; fn < NFR; ++fn) {
                const int row = wn + fn*16 + fr;
                const int sl  = (ks*4 + fq) ^ (row & 7);
                bf[fn] = *reinterpret_cast<const short8*>(&Bs[row*64 + sl*8]);
            }
#pragma unroll
            for (int fm = 0; fm < 2; ++fm)
#pragma unroll
                for (int fn = 0; fn < NFR; ++fn)
                    acc[fm][fn] = __builtin_amdgcn_mfma_f32_16x16x32_bf16(
                        af[fm], bf[fn], acc[fm][fn], 0, 0, 0);
        }
    }

#pragma unroll
    for (int fm = 0; fm < 2; ++fm)
#pragma unroll
        for (int fn = 0; fn < NFR; ++fn) {
            const int coll = wn + fn*16 + fr;
            const float bia = biasb[colbase + coll];
#pragma unroll
            for (int r = 0; r < 4; ++r) {
                const int row = bm*64 + wm + fm*16 + fq*4 + r;
                float v = acc[fm][fn][r] + bia;
                if (ACT == 1) v = fmaxf(v, 0.f);
                if (ACT == 2) v = 1.f / (1.f + __expf(-v));
                Cb[(size_t)row*ldcb + colbase + coll] = v;
            }
        }
}

// ---------------------------------------------------------------------------
// prep: t = target; q = target + pos
// ---------------------------------------------------------------------------
__global__ __launch_bounds__(256)
void prep0(const float* __restrict__ target, const float* __restrict__ pos,
           float* __restrict__ t, float* __restrict__ q)
{
    const size_t idx = (size_t)blockIdx.x*256 + threadIdx.x;
    const float v = target[idx];
    t[idx] = v;
    q[idx] = v + pos[idx];
}

// flat f32 -> bf16, vectorized x4 (value conversion, once per replay)
__global__ __launch_bounds__(256)
void cvt_flat4(const float* __restrict__ src, ushort_t* __restrict__ dst, int n4)
{
    for (int i = blockIdx.x*256 + threadIdx.x; i < n4; i += gridDim.x*256) {
        const float4 v = reinterpret_cast<const float4*>(src)[i];
        ushort_t o[4] = {(ushort_t)bf16r(v.x), (ushort_t)bf16r(v.y),
                         (ushort_t)bf16r(v.z), (ushort_t)bf16r(v.w)};
        *reinterpret_cast<uint2*>(dst + (size_t)i*4) = *reinterpret_cast<uint2*>(o);
    }
}

// ---------------------------------------------------------------------------
// Fused MHA, keys-across-lanes (R3-proven). One block per (b,h,quarter).
// ---------------------------------------------------------------------------
__global__ __launch_bounds__(256)
void mha_block(const float* __restrict__ qkv, float* __restrict__ o)
{
    const int blk = blockIdx.x;          // ((b*8+h)*4 + quarter)
    const int quarter = blk & 3;
    const int bh = blk >> 2;
    const int b = bh >> 3, h = bh & 7;
    const int tid = threadIdx.x;
    const int lane = tid & 63;
    const int w = tid >> 6;

    __shared__ uint32_t Kp[16][320];     // [d-pair][key], pad 300..319 = 0
    __shared__ uint32_t Vp[150][32];     // [key-pair][d]
    __shared__ float    ws[4][304];      // per-wave softmax weights
    const float* base = qkv + (size_t)b * LQ * 768;
    const int hc = h * 32;

    for (int idx = tid; idx < 300*16; idx += 256) {
        const int j = idx >> 4, d2 = idx & 15;
        const float2 kv = *reinterpret_cast<const float2*>(base + (size_t)j*768 + 256 + hc + 2*d2);
        Kp[d2][j] = (bf16r(kv.y) << 16) | bf16r(kv.x);
    }
    for (int idx = tid; idx < 16*20; idx += 256)
        Kp[idx/20][300 + idx%20] = 0;
    for (int idx = tid; idx < 150*32; idx += 256) {
        const int jp = idx >> 5, d = idx & 31;
        const float lo = base[(size_t)(2*jp  )*768 + 512 + hc + d];
        const float hi = base[(size_t)(2*jp+1)*768 + 512 + hc + d];
        Vp[jp][d] = (bf16r(hi) << 16) | bf16r(lo);
    }
    __syncthreads();

    const float scale = 0.17677669529663687f;   // 1/sqrt(32)
    const int qbase = quarter * 75;
    for (int il = w; il < 75; il += 4) {
        const int iq = qbase + il;
        const float2* qrow = reinterpret_cast<const float2*>(base + (size_t)iq*768 + hc);

        float s0=0.f, s1=0.f, s2=0.f, s3=0.f, s4=0.f;
#pragma unroll
        for (int d2 = 0; d2 < 16; ++d2) {
            const float2 q2 = qrow[d2];
            uint32_t k;
            k = Kp[d2][lane      ]; s0 += lof(k)*q2.x + hif(k)*q2.y;
            k = Kp[d2][lane +  64]; s1 += lof(k)*q2.x + hif(k)*q2.y;
            k = Kp[d2][lane + 128]; s2 += lof(k)*q2.x + hif(k)*q2.y;
            k = Kp[d2][lane + 192]; s3 += lof(k)*q2.x + hif(k)*q2.y;
            k = Kp[d2][lane + 256]; s4 += lof(k)*q2.x + hif(k)*q2.y;
        }
        s0 *= scale; s1 *= scale; s2 *= scale; s3 *= scale;
        s4 = (lane < 44) ? s4*scale : -3e38f;

        float m = fmaxf(fmaxf(fmaxf(s0,s1), fmaxf(s2,s3)), s4);
#pragma unroll
        for (int off = 32; off; off >>= 1) m = fmaxf(m, __shfl_xor(m, off));
        const float e0 = __expf(s0-m), e1 = __expf(s1-m), e2 = __expf(s2-m), e3 = __expf(s3-m);
        const float e4 = (lane < 44) ? __expf(s4-m) : 0.f;
        float sum = e0+e1+e2+e3+e4;
#pragma unroll
        for (int off = 32; off; off >>= 1) sum += __shfl_xor(sum, off);
        const float inv = 1.f / sum;
        ws[w][lane      ] = e0;
        ws[w][lane +  64] = e1;
        ws[w][lane + 128] = e2;
        ws[w][lane + 192] = e3;
        if (lane < 44) ws[w][lane + 256] = e4;

        const int half = lane >> 5, d = lane & 31;
        float acc = 0.f;
#pragma unroll 5
        for (int jp = half*75; jp < half*75 + 75; ++jp) {
            const float2 w2 = *reinterpret_cast<const float2*>(&ws[w][2*jp]);
            const uint32_t v2 = Vp[jp][d];
            acc += lof(v2)*w2.x + hif(v2)*w2.y;
        }
        acc += __shfl_down(acc, 32);
        if (lane < 32)
            o[((size_t)(b*LQ + iq))*256 + hc + d] = acc * inv;
    }
}

// ---------------------------------------------------------------------------
__device__ __forceinline__ float blk_sum(float v, float* red)
{
#pragma unroll
    for (int off = 32; off; off >>= 1) v += __shfl_down(v, off, 64);
    const int lane = threadIdx.x & 63, w = threadIdx.x >> 6;
    if (lane == 0) red[w] = v;
    __syncthreads();
    const float s = red[0] + red[1] + red[2] + red[3];
    __syncthreads();
    return s;
}

// t_out = LN(t + t2) ; q_out = t_out + pos
__global__ __launch_bounds__(256)
void ln_res_pos(const float* __restrict__ t, const float* __restrict__ t2,
                const float* __restrict__ g, const float* __restrict__ bb,
                const float* __restrict__ pos,
                float* __restrict__ t_out, float* __restrict__ q_out)
{
    __shared__ float red[4];
    const size_t idx = (size_t)blockIdx.x*256 + threadIdx.x;
    const float x = t[idx] + t2[idx];
    const float mean = blk_sum(x, red) * (1.f/256.f);
    const float c = x - mean;
    const float var = blk_sum(c*c, red) * (1.f/256.f);
    const float y = c * rsqrtf(var + 1e-5f) * g[threadIdx.x] + bb[threadIdx.x];
    t_out[idx] = y;
    q_out[idx] = y + pos[idx];
}

// t_out = LN(g1*t + g2*t2)
__global__ __launch_bounds__(256)
void gate_ln(const float* __restrict__ t, const float* __restrict__ t2,
             const float* __restrict__ gates,
             const float* __restrict__ g, const float* __restrict__ bb,
             float* __restrict__ t_out)
{
    __shared__ float red[4];
    const int row = blockIdx.x, dd = threadIdx.x;
    const size_t idx = (size_t)row*256 + dd;
    const float g1 = gates[(size_t)row*512 + dd];
    const float g2 = gates[(size_t)row*512 + 256 + dd];
    const float x = g1 * t[idx] + g2 * t2[idx];
    const float mean = blk_sum(x, red) * (1.f/256.f);
    const float c = x - mean;
    const float var = blk_sum(c*c, red) * (1.f/256.f);
    t_out[idx] = c * rsqrtf(var + 1e-5f) * g[dd] + bb[dd];
}

// out = LN(clip(t + t2)) ; if q_out != null also q_out = out + pos
__global__ __launch_bounds__(256)
void ln_clip(const float* __restrict__ t, const float* __restrict__ t2,
             const float* __restrict__ g, const float* __restrict__ bb,
             const float* __restrict__ pos,
             float* __restrict__ outp, float* __restrict__ q_out)
{
    __shared__ float red[4];
    const size_t idx = (size_t)blockIdx.x*256 + threadIdx.x;
    float x = t[idx] + t2[idx];
    x = fminf(fmaxf(x, -65504.f), 65504.f);
    const float mean = blk_sum(x, red) * (1.f/256.f);
    const float c = x - mean;
    const float var = blk_sum(c*c, red) * (1.f/256.f);
    const float y = c * rsqrtf(var + 1e-5f) * g[threadIdx.x] + bb[threadIdx.x];
    outp[idx] = y;
    if (q_out != nullptr) q_out[idx] = y + pos[idx];
}

// ---------------------------------------------------------------------------
// MS-deformable attention gather with fused attention-weight softmax.
// so: [bq][256], awl: [bq][128] logits. One block per (b,q) = 8 heads x 32 d.
// VBF: value is bf16 (halved gather traffic) vs f32.
// ---------------------------------------------------------------------------
template<int VBF>
__global__ __launch_bounds__(256)
void deform_attn(const void* __restrict__ value_p, const float* __restrict__ refp,
                 const float* __restrict__ so, const float* __restrict__ awl,
                 float* __restrict__ outp)
{
    const int bq = blockIdx.x;
    const int b  = bq / LQ;
    const int tid = threadIdx.x;
    __shared__ int   s_idx[128][4];
    __shared__ float s_w[128][4];
    if (tid < 128) {
        const int hp = tid;
        const int p  = hp & 15;
        const int lvl = p >> 2;
        const float Wl = (lvl == 0) ? 80.f : (lvl == 1) ? 40.f : (lvl == 2) ? 20.f : 10.f;
        const float Hl = Wl;
        const int off  = (lvl == 0) ? 0 : (lvl == 1) ? 6400 : (lvl == 2) ? 8000 : 8400;
        // fused softmax over the 16 points of this head (16-lane groups)
        const float logit = awl[(size_t)bq*128 + hp];
        float m = logit;
#pragma unroll
        for (int o = 8; o; o >>= 1) m = fmaxf(m, __shfl_xor(m, o, 16));
        const float e = __expf(logit - m);
        float ssum = e;
#pragma unroll
        for (int o = 8; o; o >>= 1) ssum += __shfl_xor(ssum, o, 16);
        const float a = e / ssum;

        const float cx = refp[bq*4+0], cy = refp[bq*4+1];
        const float rw = refp[bq*4+2], rh = refp[bq*4+3];
        const float lx = cx + so[(size_t)bq*256 + hp*2    ] * rw * 0.125f;
        const float ly = cy + so[(size_t)bq*256 + hp*2 + 1] * rh * 0.125f;
        const float x = lx * Wl - 0.5f;
        const float y = ly * Hl - 0.5f;
        const float x0 = floorf(x), y0 = floorf(y);
        const float wx1 = x - x0, wx0 = 1.f - wx1;
        const float wy1 = y - y0, wy0 = 1.f - wy1;
        const float xs[2]  = {x0, x0 + 1.f}, ys[2]  = {y0, y0 + 1.f};
        const float wxs[2] = {wx0, wx1},     wys[2] = {wy0, wy1};
#pragma unroll
        for (int cyi = 0; cyi < 2; ++cyi)
#pragma unroll
            for (int cxi = 0; cxi < 2; ++cxi) {
                const float xi = xs[cxi], yi = ys[cyi];
                const bool valid = (xi >= 0.f) && (xi <= Wl - 1.f) &&
                                   (yi >= 0.f) && (yi <= Hl - 1.f);
                const float xc = fminf(fmaxf(xi, 0.f), Wl - 1.f);
                const float yc = fminf(fmaxf(yi, 0.f), Hl - 1.f);
                const int c = cyi*2 + cxi;
                s_idx[hp][c] = (int)(yc*Wl + xc) + off;
                s_w[hp][c]   = valid ? (wxs[cxi]*wys[cyi]*a) : 0.f;
            }
    }
    __syncthreads();
    const int h = tid >> 5, d = tid & 31;
    const int col = h*32 + d;
    float acc = 0.f;
    if (VBF) {
        const ushort_t* vb = (const ushort_t*)value_p + (size_t)b * LEN_V * 256;
#pragma unroll
        for (int p = 0; p < 16; ++p) {
            const int hp = (h << 4) | p;
#pragma unroll
            for (int c = 0; c < 4; ++c)
                acc += s_w[hp][c] *
                       __uint_as_float(((uint32_t)vb[(size_t)s_idx[hp][c]*256 + col]) << 16);
        }
    } else {
        const float* vb = (const float*)value_p + (size_t)b * LEN_V * 256;
#pragma unroll
        for (int p = 0; p < 16; ++p) {
            const int hp = (h << 4) | p;
#pragma unroll
            for (int c = 0; c < 4; ++c)
                acc += s_w[hp][c] * vb[(size_t)s_idx[hp][c]*256 + col];
        }
    }
    outp[(size_t)bq*256 + col] = acc;
}

// ---------------------------------------------------------------------------
extern "C" void kernel_launch(void* const* d_in, const int* in_sizes, int n_in,
                              void* d_out, int out_size, void* d_ws, size_t ws_size,
                              hipStream_t stream)
{
    (void)in_sizes; (void)n_in; (void)out_size;
    const float* target = (const float*)d_in[0];
    const float* refp   = (const float*)d_in[1];
    const float* value  = (const float*)d_in[2];
    const float* qpos   = (const float*)d_in[3];
    const float* Wqkv   = (const float*)d_in[4];
    const float* bqkv   = (const float*)d_in[5];
    const float* Wo     = (const float*)d_in[6];
    const float* bo     = (const float*)d_in[7];
    const float* n1g    = (const float*)d_in[8];
    const float* n1b    = (const float*)d_in[9];
    const float* soW    = (const float*)d_in[10];
    const float* sob    = (const float*)d_in[11];
    const float* awW    = (const float*)d_in[12];
    const float* awb    = (const float*)d_in[13];
    const float* gW     = (const float*)d_in[14];
    const float* gb     = (const float*)d_in[15];
    const float* gng    = (const float*)d_in[16];
    const float* gnb    = (const float*)d_in[17];
    const float* l1W    = (const float*)d_in[18];
    const float* l1b    = (const float*)d_in[19];
    const float* l2W    = (const float*)d_in[20];
    const float* l2b    = (const float*)d_in[21];
    const float* n3g    = (const float*)d_in[22];
    const float* n3b    = (const float*)d_in[23];

    // ---- workspace carve; region R is time-shared: qkv|o -> so|aw -> gates -> hid
    float* p = (float*)d_ws;
    float* t_buf = p;  p += (size_t)ROWS*D;        // 4.9 MB, persistent
    float* q_buf = p;  p += (size_t)ROWS*D;        // 4.9 MB, persistent
    float* R     = p;  p += (size_t)ROWS*1024;     // 19.7 MB, phase-shared
    float* t2    = p;  p += (size_t)ROWS*D;        // 4.9 MB

    float* qkv   = R;                              // ROWS*768   (phase 1)
    float* o_buf = R + (size_t)ROWS*768;           // ROWS*256   (phase 1)
    float* so_b  = R;                              // ROWS*256   (phase 2)
    float* aw_b  = R + (size_t)ROWS*256;           // ROWS*128   (phase 2)
    float* gates = R;                              // ROWS*512   (phase 3)
    float* hid   = R;                              // ROWS*1024  (phase 4)

    const size_t base_bytes = (size_t)((char*)p - (char*)d_ws);
    const size_t val_elems  = (size_t)BS*LEN_V*256;
    ushort_t* val_bf = (ushort_t*)p;
    const bool use_vbf = (ws_size >= base_bytes + val_elems*2);

    if (use_vbf)
        cvt_flat4<<<2048, 256, 0, stream>>>(value, val_bf, (int)(val_elems/4));
    prep0<<<ROWS, 256, 0, stream>>>(target, qpos, t_buf, q_buf);

    for (int i = 0; i < 6; ++i) {
        const float* Wqkv_i = Wqkv + (size_t)i*768*256;
        const float* bqkv_i = bqkv + (size_t)i*768;
        const float* Wo_i   = Wo   + (size_t)i*256*256;
        const float* bo_i   = bo   + (size_t)i*256;
        const float* n1g_i  = n1g  + (size_t)i*256;
        const float* n1b_i  = n1b  + (size_t)i*256;
        const float* soW_i  = soW  + (size_t)i*256*256;
        const float* sob_i  = sob  + (size_t)i*256;
        const float* awW_i  = awW  + (size_t)i*128*256;
        const float* awb_i  = awb  + (size_t)i*128;
        const float* gW_i   = gW   + (size_t)i*512*512;
        const float* gb_i   = gb   + (size_t)i*512;
        const float* gng_i  = gng  + (size_t)i*256;
        const float* gnb_i  = gnb  + (size_t)i*256;
        const float* l1W_i  = l1W  + (size_t)i*1024*256;
        const float* l1b_i  = l1b  + (size_t)i*1024;
        const float* l2W_i  = l2W  + (size_t)i*256*1024;
        const float* l2b_i  = l2b  + (size_t)i*256;
        const float* n3g_i  = n3g  + (size_t)i*256;
        const float* n3b_i  = n3b  + (size_t)i*256;

        // ---- MHA: merged QKV GEMM, BN=128 (bn<4: Q|K from q_buf; bn>=4: V from t_buf)
        gemm_f32<0,128><<<dim3(75, 6), 256, 0, stream>>>(
            q_buf, t_buf, 4, 256,  nullptr, 0, 0,
            Wqkv_i, nullptr, 999,  bqkv_i, nullptr,
            qkv, 768, nullptr, 0,  256);
        mha_block<<<BS*NH*4, 256, 0, stream>>>(qkv, o_buf);
        gemm_f32<0,64><<<dim3(75, 4), 256, 0, stream>>>(
            o_buf, o_buf, 999, 256,  nullptr, 0, 0,
            Wo_i, nullptr, 999,  bo_i, nullptr,
            t2, 256, nullptr, 0,  256);
        ln_res_pos<<<ROWS, 256, 0, stream>>>(t_buf, t2, n1g_i, n1b_i, qpos, t_buf, q_buf);

        // ---- deformable attention: merged so|aw GEMM (bn<4: so; bn>=4: aw)
        gemm_f32<0,64><<<dim3(75, 6), 256, 0, stream>>>(
            q_buf, q_buf, 999, 256,  nullptr, 0, 0,
            soW_i, awW_i, 4,  sob_i, awb_i,
            so_b, 256, aw_b, 128,  256);
        if (use_vbf)
            deform_attn<1><<<ROWS, 256, 0, stream>>>(val_bf, refp, so_b, aw_b, t2);
        else
            deform_attn<0><<<ROWS, 256, 0, stream>>>(value, refp, so_b, aw_b, t2);

        // ---- gating: BN=128, concat fused via A2 k-split
        gemm_f32<2,128><<<dim3(75, 4), 256, 0, stream>>>(
            t_buf, t_buf, 999, 256,  t2, 256, 256,
            gW_i, nullptr, 999,  gb_i, nullptr,
            gates, 512, nullptr, 0,  512);
        gate_ln<<<ROWS, 256, 0, stream>>>(t_buf, t2, gates, gng_i, gnb_i, t_buf);

        // ---- FFN: l1 BN=128, l2 BN=64 (deep K)
        gemm_f32<1,128><<<dim3(75, 8), 256, 0, stream>>>(
            t_buf, t_buf, 999, 256,  nullptr, 0, 0,
            l1W_i, nullptr, 999,  l1b_i, nullptr,
            hid, 1024, nullptr, 0,  256);
        gemm_f32<0,64><<<dim3(75, 4), 256, 0, stream>>>(
            hid, hid, 999, 1024,  nullptr, 0, 0,
            l2W_i, nullptr, 999,  l2b_i, nullptr,
            t2, 256, nullptr, 0,  1024);
        ln_clip<<<ROWS, 256, 0, stream>>>(t_buf, t2, n3g_i, n3b_i, qpos,
                                          (i == 5) ? (float*)d_out : t_buf,
                                          (i < 5) ? q_buf : nullptr);
    }
}

// Round 8
// 1335.155 us; speedup vs baseline: 1.0668x; 1.0668x over previous
//
#include <hip/hip_runtime.h>

#define BS 16
#define LQ 300
#define D 256
#define NH 8
#define HD 32
#define DFF 1024
#define ROWS (BS*LQ)    // 4800
#define LEN_V 8500

typedef __attribute__((ext_vector_type(8))) short short8;
typedef __attribute__((ext_vector_type(4))) float f32x4;
typedef unsigned short ushort_t;

// bf16 round-to-nearest-even (low 16 bits)
__device__ __forceinline__ uint32_t bf16r(float x)
{
    const uint32_t u = __float_as_uint(x);
    return (u + 0x7fffu + ((u >> 16) & 1u)) >> 16;
}
__device__ __forceinline__ float lof(uint32_t p) { return __uint_as_float(p << 16); }
__device__ __forceinline__ float hif(uint32_t p) { return __uint_as_float(p & 0xffff0000u); }

// ---------------------------------------------------------------------------
// MFMA GEMM — EXACT R6 version (tile 64x64, BK=64, proven staging).
// Per-bn selects (all wave-uniform, resolved once at entry):
//   A-select:  bn >= bnsplit_a -> Aalt           (merged QKV)
//   W/C-select: bn >= bnw -> W2/bias2/C2/ldc2    (merged so|aw)
//   k-concat:  A2 != null && kg >= ksplit -> A2  (gates [t|t2] fusion)
// ACT: 0=none 1=relu 2=sigmoid
// ---------------------------------------------------------------------------
template<int ACT>
__global__ __launch_bounds__(256)
void gemm_f32(const float* __restrict__ A, const float* __restrict__ Aalt,
              int bnsplit_a, int lda,
              const float* __restrict__ A2, int lda2, int ksplit,
              const float* __restrict__ W, const float* __restrict__ W2, int bnw,
              const float* __restrict__ bias, const float* __restrict__ bias2,
              float* __restrict__ C, int ldc, float* __restrict__ C2, int ldc2,
              int K)
{
    __shared__ __align__(16) unsigned short As[64*64];   // [row][slot^], 128B rows
    __shared__ __align__(16) unsigned short Bs[64*64];
    const int tid  = threadIdx.x;
    const int bm   = blockIdx.x, bn = blockIdx.y;
    const int lane = tid & 63;
    const int w    = tid >> 6;
    const int wm   = (w >> 1) * 32, wn = (w & 1) * 32;
    const int fr   = lane & 15;     // fragment row/col
    const int fq   = lane >> 4;     // k-quad

    const int srow = tid >> 2;      // staging row 0..63
    const int sg   = tid & 3;       // staging slot sub-index

    // wave-uniform selects
    if (bn >= bnsplit_a) A = Aalt;
    const float* Wb; const float* biasb; float* Cb; int ldcb; int colbase;
    if (bn < bnw) {
        Wb = W  + (size_t)bn*64*K;        biasb = bias;
        Cb = C;  ldcb = ldc;  colbase = bn*64;
    } else {
        Wb = W2 + (size_t)(bn-bnw)*64*K;  biasb = bias2;
        Cb = C2; ldcb = ldc2; colbase = (bn-bnw)*64;
    }

    f32x4 acc[2][2] = {};

    for (int k0 = 0; k0 < K; k0 += 64) {
        float4 a0[2], a1[2], w0[2], w1[2];
#pragma unroll
        for (int p = 0; p < 2; ++p) {
            const int slot = sg + 4*p;        // 0..7 (8 elems each)
            const int kg   = k0 + slot*8;
            const float* Asrc = (A2 != nullptr && kg >= ksplit)
                ? (A2 + (size_t)(bm*64 + srow)*lda2 + (kg - ksplit))
                : (A  + (size_t)(bm*64 + srow)*lda  + kg);
            a0[p] = *reinterpret_cast<const float4*>(Asrc);
            a1[p] = *reinterpret_cast<const float4*>(Asrc + 4);
            const float* Wsrc = Wb + (size_t)srow*K + kg;
            w0[p] = *reinterpret_cast<const float4*>(Wsrc);
            w1[p] = *reinterpret_cast<const float4*>(Wsrc + 4);
        }
        __syncthreads();
#pragma unroll
        for (int p = 0; p < 2; ++p) {
            const int slot = (sg + 4*p) ^ (srow & 7);
            uint32_t pk[4];
            pk[0] = bf16r(a0[p].x) | (bf16r(a0[p].y) << 16);
            pk[1] = bf16r(a0[p].z) | (bf16r(a0[p].w) << 16);
            pk[2] = bf16r(a1[p].x) | (bf16r(a1[p].y) << 16);
            pk[3] = bf16r(a1[p].z) | (bf16r(a1[p].w) << 16);
            *reinterpret_cast<uint4*>(&As[srow*64 + slot*8]) =
                make_uint4(pk[0], pk[1], pk[2], pk[3]);
            pk[0] = bf16r(w0[p].x) | (bf16r(w0[p].y) << 16);
            pk[1] = bf16r(w0[p].z) | (bf16r(w0[p].w) << 16);
            pk[2] = bf16r(w1[p].x) | (bf16r(w1[p].y) << 16);
            pk[3] = bf16r(w1[p].z) | (bf16r(w1[p].w) << 16);
            *reinterpret_cast<uint4*>(&Bs[srow*64 + slot*8]) =
                make_uint4(pk[0], pk[1], pk[2], pk[3]);
        }
        __syncthreads();
#pragma unroll
        for (int ks = 0; ks < 2; ++ks) {
            short8 af[2], bf[2];
#pragma unroll
            for (int fm = 0; fm < 2; ++fm) {
                const int row = wm + fm*16 + fr;
                const int slot = (ks*4 + fq) ^ (row & 7);
                af[fm] = *reinterpret_cast<const short8*>(&As[row*64 + slot*8]);
            }
#pragma unroll
            for (int fn = 0; fn < 2; ++fn) {
                const int row = wn + fn*16 + fr;
                const int slot = (ks*4 + fq) ^ (row & 7);
                bf[fn] = *reinterpret_cast<const short8*>(&Bs[row*64 + slot*8]);
            }
#pragma unroll
            for (int fm = 0; fm < 2; ++fm)
#pragma unroll
                for (int fn = 0; fn < 2; ++fn)
                    acc[fm][fn] = __builtin_amdgcn_mfma_f32_16x16x32_bf16(
                        af[fm], bf[fn], acc[fm][fn], 0, 0, 0);
        }
    }

#pragma unroll
    for (int fm = 0; fm < 2; ++fm)
#pragma unroll
        for (int fn = 0; fn < 2; ++fn) {
            const int coll = wn + fn*16 + fr;
            const float bia = biasb[colbase + coll];
#pragma unroll
            for (int r = 0; r < 4; ++r) {
                const int row = bm*64 + wm + fm*16 + fq*4 + r;
                float v = acc[fm][fn][r] + bia;
                if (ACT == 1) v = fmaxf(v, 0.f);
                if (ACT == 2) v = 1.f / (1.f + __expf(-v));
                Cb[(size_t)row*ldcb + colbase + coll] = v;
            }
        }
}

// ---------------------------------------------------------------------------
// prep: t = target; q = target + pos
// ---------------------------------------------------------------------------
__global__ __launch_bounds__(256)
void prep0(const float* __restrict__ target, const float* __restrict__ pos,
           float* __restrict__ t, float* __restrict__ q)
{
    const size_t idx = (size_t)blockIdx.x*256 + threadIdx.x;
    const float v = target[idx];
    t[idx] = v;
    q[idx] = v + pos[idx];
}

// flat f32 -> bf16, vectorized x4 (value conversion, once per replay)
__global__ __launch_bounds__(256)
void cvt_flat4(const float* __restrict__ src, ushort_t* __restrict__ dst, int n4)
{
    for (int i = blockIdx.x*256 + threadIdx.x; i < n4; i += gridDim.x*256) {
        const float4 v = reinterpret_cast<const float4*>(src)[i];
        ushort_t o[4] = {(ushort_t)bf16r(v.x), (ushort_t)bf16r(v.y),
                         (ushort_t)bf16r(v.z), (ushort_t)bf16r(v.w)};
        *reinterpret_cast<uint2*>(dst + (size_t)i*4) = *reinterpret_cast<uint2*>(o);
    }
}

// ---------------------------------------------------------------------------
// Fused MHA, keys-across-lanes (R3-proven). One block per (b,h,quarter).
// ---------------------------------------------------------------------------
__global__ __launch_bounds__(256)
void mha_block(const float* __restrict__ qkv, float* __restrict__ o)
{
    const int blk = blockIdx.x;          // ((b*8+h)*4 + quarter)
    const int quarter = blk & 3;
    const int bh = blk >> 2;
    const int b = bh >> 3, h = bh & 7;
    const int tid = threadIdx.x;
    const int lane = tid & 63;
    const int w = tid >> 6;

    __shared__ uint32_t Kp[16][320];     // [d-pair][key], pad 300..319 = 0
    __shared__ uint32_t Vp[150][32];     // [key-pair][d]
    __shared__ float    ws[4][304];      // per-wave softmax weights
    const float* base = qkv + (size_t)b * LQ * 768;
    const int hc = h * 32;

    for (int idx = tid; idx < 300*16; idx += 256) {
        const int j = idx >> 4, d2 = idx & 15;
        const float2 kv = *reinterpret_cast<const float2*>(base + (size_t)j*768 + 256 + hc + 2*d2);
        Kp[d2][j] = (bf16r(kv.y) << 16) | bf16r(kv.x);
    }
    for (int idx = tid; idx < 16*20; idx += 256)
        Kp[idx/20][300 + idx%20] = 0;
    for (int idx = tid; idx < 150*32; idx += 256) {
        const int jp = idx >> 5, d = idx & 31;
        const float lo = base[(size_t)(2*jp  )*768 + 512 + hc + d];
        const float hi = base[(size_t)(2*jp+1)*768 + 512 + hc + d];
        Vp[jp][d] = (bf16r(hi) << 16) | bf16r(lo);
    }
    __syncthreads();

    const float scale = 0.17677669529663687f;   // 1/sqrt(32)
    const int qbase = quarter * 75;
    for (int il = w; il < 75; il += 4) {
        const int iq = qbase + il;
        const float2* qrow = reinterpret_cast<const float2*>(base + (size_t)iq*768 + hc);

        float s0=0.f, s1=0.f, s2=0.f, s3=0.f, s4=0.f;
#pragma unroll
        for (int d2 = 0; d2 < 16; ++d2) {
            const float2 q2 = qrow[d2];
            uint32_t k;
            k = Kp[d2][lane      ]; s0 += lof(k)*q2.x + hif(k)*q2.y;
            k = Kp[d2][lane +  64]; s1 += lof(k)*q2.x + hif(k)*q2.y;
            k = Kp[d2][lane + 128]; s2 += lof(k)*q2.x + hif(k)*q2.y;
            k = Kp[d2][lane + 192]; s3 += lof(k)*q2.x + hif(k)*q2.y;
            k = Kp[d2][lane + 256]; s4 += lof(k)*q2.x + hif(k)*q2.y;
        }
        s0 *= scale; s1 *= scale; s2 *= scale; s3 *= scale;
        s4 = (lane < 44) ? s4*scale : -3e38f;

        float m = fmaxf(fmaxf(fmaxf(s0,s1), fmaxf(s2,s3)), s4);
#pragma unroll
        for (int off = 32; off; off >>= 1) m = fmaxf(m, __shfl_xor(m, off));
        const float e0 = __expf(s0-m), e1 = __expf(s1-m), e2 = __expf(s2-m), e3 = __expf(s3-m);
        const float e4 = (lane < 44) ? __expf(s4-m) : 0.f;
        float sum = e0+e1+e2+e3+e4;
#pragma unroll
        for (int off = 32; off; off >>= 1) sum += __shfl_xor(sum, off);
        const float inv = 1.f / sum;
        ws[w][lane      ] = e0;
        ws[w][lane +  64] = e1;
        ws[w][lane + 128] = e2;
        ws[w][lane + 192] = e3;
        if (lane < 44) ws[w][lane + 256] = e4;

        const int half = lane >> 5, d = lane & 31;
        float acc = 0.f;
#pragma unroll 5
        for (int jp = half*75; jp < half*75 + 75; ++jp) {
            const float2 w2 = *reinterpret_cast<const float2*>(&ws[w][2*jp]);
            const uint32_t v2 = Vp[jp][d];
            acc += lof(v2)*w2.x + hif(v2)*w2.y;
        }
        acc += __shfl_down(acc, 32);
        if (lane < 32)
            o[((size_t)(b*LQ + iq))*256 + hc + d] = acc * inv;
    }
}

// ---------------------------------------------------------------------------
__device__ __forceinline__ float blk_sum(float v, float* red)
{
#pragma unroll
    for (int off = 32; off; off >>= 1) v += __shfl_down(v, off, 64);
    const int lane = threadIdx.x & 63, w = threadIdx.x >> 6;
    if (lane == 0) red[w] = v;
    __syncthreads();
    const float s = red[0] + red[1] + red[2] + red[3];
    __syncthreads();
    return s;
}

// t_out = LN(t + t2) ; q_out = t_out + pos
__global__ __launch_bounds__(256)
void ln_res_pos(const float* __restrict__ t, const float* __restrict__ t2,
                const float* __restrict__ g, const float* __restrict__ bb,
                const float* __restrict__ pos,
                float* __restrict__ t_out, float* __restrict__ q_out)
{
    __shared__ float red[4];
    const size_t idx = (size_t)blockIdx.x*256 + threadIdx.x;
    const float x = t[idx] + t2[idx];
    const float mean = blk_sum(x, red) * (1.f/256.f);
    const float c = x - mean;
    const float var = blk_sum(c*c, red) * (1.f/256.f);
    const float y = c * rsqrtf(var + 1e-5f) * g[threadIdx.x] + bb[threadIdx.x];
    t_out[idx] = y;
    q_out[idx] = y + pos[idx];
}

// t_out = LN(g1*t + g2*t2)
__global__ __launch_bounds__(256)
void gate_ln(const float* __restrict__ t, const float* __restrict__ t2,
             const float* __restrict__ gates,
             const float* __restrict__ g, const float* __restrict__ bb,
             float* __restrict__ t_out)
{
    __shared__ float red[4];
    const int row = blockIdx.x, dd = threadIdx.x;
    const size_t idx = (size_t)row*256 + dd;
    const float g1 = gates[(size_t)row*512 + dd];
    const float g2 = gates[(size_t)row*512 + 256 + dd];
    const float x = g1 * t[idx] + g2 * t2[idx];
    const float mean = blk_sum(x, red) * (1.f/256.f);
    const float c = x - mean;
    const float var = blk_sum(c*c, red) * (1.f/256.f);
    t_out[idx] = c * rsqrtf(var + 1e-5f) * g[dd] + bb[dd];
}

// out = LN(clip(t + t2)) ; if q_out != null also q_out = out + pos
__global__ __launch_bounds__(256)
void ln_clip(const float* __restrict__ t, const float* __restrict__ t2,
             const float* __restrict__ g, const float* __restrict__ bb,
             const float* __restrict__ pos,
             float* __restrict__ outp, float* __restrict__ q_out)
{
    __shared__ float red[4];
    const size_t idx = (size_t)blockIdx.x*256 + threadIdx.x;
    float x = t[idx] + t2[idx];
    x = fminf(fmaxf(x, -65504.f), 65504.f);
    const float mean = blk_sum(x, red) * (1.f/256.f);
    const float c = x - mean;
    const float var = blk_sum(c*c, red) * (1.f/256.f);
    const float y = c * rsqrtf(var + 1e-5f) * g[threadIdx.x] + bb[threadIdx.x];
    outp[idx] = y;
    if (q_out != nullptr) q_out[idx] = y + pos[idx];
}

// ---------------------------------------------------------------------------
// MS-deformable attention gather with fused attention-weight softmax.
// so: [bq][256], awl: [bq][128] logits. One block per (b,q) = 8 heads x 32 d.
// VBF: value is bf16 (halved gather traffic) vs f32.
// ---------------------------------------------------------------------------
template<int VBF>
__global__ __launch_bounds__(256)
void deform_attn(const void* __restrict__ value_p, const float* __restrict__ refp,
                 const float* __restrict__ so, const float* __restrict__ awl,
                 float* __restrict__ outp)
{
    const int bq = blockIdx.x;
    const int b  = bq / LQ;
    const int tid = threadIdx.x;
    __shared__ int   s_idx[128][4];
    __shared__ float s_w[128][4];
    if (tid < 128) {
        const int hp = tid;
        const int p  = hp & 15;
        const int lvl = p >> 2;
        const float Wl = (lvl == 0) ? 80.f : (lvl == 1) ? 40.f : (lvl == 2) ? 20.f : 10.f;
        const float Hl = Wl;
        const int off  = (lvl == 0) ? 0 : (lvl == 1) ? 6400 : (lvl == 2) ? 8000 : 8400;
        // fused softmax over the 16 points of this head (16-lane groups)
        const float logit = awl[(size_t)bq*128 + hp];
        float m = logit;
#pragma unroll
        for (int o = 8; o; o >>= 1) m = fmaxf(m, __shfl_xor(m, o, 16));
        const float e = __expf(logit - m);
        float ssum = e;
#pragma unroll
        for (int o = 8; o; o >>= 1) ssum += __shfl_xor(ssum, o, 16);
        const float a = e / ssum;

        const float cx = refp[bq*4+0], cy = refp[bq*4+1];
        const float rw = refp[bq*4+2], rh = refp[bq*4+3];
        const float lx = cx + so[(size_t)bq*256 + hp*2    ] * rw * 0.125f;
        const float ly = cy + so[(size_t)bq*256 + hp*2 + 1] * rh * 0.125f;
        const float x = lx * Wl - 0.5f;
        const float y = ly * Hl - 0.5f;
        const float x0 = floorf(x), y0 = floorf(y);
        const float wx1 = x - x0, wx0 = 1.f - wx1;
        const float wy1 = y - y0, wy0 = 1.f - wy1;
        const float xs[2]  = {x0, x0 + 1.f}, ys[2]  = {y0, y0 + 1.f};
        const float wxs[2] = {wx0, wx1},     wys[2] = {wy0, wy1};
#pragma unroll
        for (int cyi = 0; cyi < 2; ++cyi)
#pragma unroll
            for (int cxi = 0; cxi < 2; ++cxi) {
                const float xi = xs[cxi], yi = ys[cyi];
                const bool valid = (xi >= 0.f) && (xi <= Wl - 1.f) &&
                                   (yi >= 0.f) && (yi <= Hl - 1.f);
                const float xc = fminf(fmaxf(xi, 0.f), Wl - 1.f);
                const float yc = fminf(fmaxf(yi, 0.f), Hl - 1.f);
                const int c = cyi*2 + cxi;
                s_idx[hp][c] = (int)(yc*Wl + xc) + off;
                s_w[hp][c]   = valid ? (wxs[cxi]*wys[cyi]*a) : 0.f;
            }
    }
    __syncthreads();
    const int h = tid >> 5, d = tid & 31;
    const int col = h*32 + d;
    float acc = 0.f;
    if (VBF) {
        const ushort_t* vb = (const ushort_t*)value_p + (size_t)b * LEN_V * 256;
#pragma unroll
        for (int p = 0; p < 16; ++p) {
            const int hp = (h << 4) | p;
#pragma unroll
            for (int c = 0; c < 4; ++c)
                acc += s_w[hp][c] *
                       __uint_as_float(((uint32_t)vb[(size_t)s_idx[hp][c]*256 + col]) << 16);
        }
    } else {
        const float* vb = (const float*)value_p + (size_t)b * LEN_V * 256;
#pragma unroll
        for (int p = 0; p < 16; ++p) {
            const int hp = (h << 4) | p;
#pragma unroll
            for (int c = 0; c < 4; ++c)
                acc += s_w[hp][c] * vb[(size_t)s_idx[hp][c]*256 + col];
        }
    }
    outp[(size_t)bq*256 + col] = acc;
}

// ---------------------------------------------------------------------------
extern "C" void kernel_launch(void* const* d_in, const int* in_sizes, int n_in,
                              void* d_out, int out_size, void* d_ws, size_t ws_size,
                              hipStream_t stream)
{
    (void)in_sizes; (void)n_in; (void)out_size;
    const float* target = (const float*)d_in[0];
    const float* refp   = (const float*)d_in[1];
    const float* value  = (const float*)d_in[2];
    const float* qpos   = (const float*)d_in[3];
    const float* Wqkv   = (const float*)d_in[4];
    const float* bqkv   = (const float*)d_in[5];
    const float* Wo     = (const float*)d_in[6];
    const float* bo     = (const float*)d_in[7];
    const float* n1g    = (const float*)d_in[8];
    const float* n1b    = (const float*)d_in[9];
    const float* soW    = (const float*)d_in[10];
    const float* sob    = (const float*)d_in[11];
    const float* awW    = (const float*)d_in[12];
    const float* awb    = (const float*)d_in[13];
    const float* gW     = (const float*)d_in[14];
    const float* gb     = (const float*)d_in[15];
    const float* gng    = (const float*)d_in[16];
    const float* gnb    = (const float*)d_in[17];
    const float* l1W    = (const float*)d_in[18];
    const float* l1b    = (const float*)d_in[19];
    const float* l2W    = (const float*)d_in[20];
    const float* l2b    = (const float*)d_in[21];
    const float* n3g    = (const float*)d_in[22];
    const float* n3b    = (const float*)d_in[23];

    // ---- workspace carve; region R is time-shared: qkv|o -> so|aw -> gates -> hid
    float* p = (float*)d_ws;
    float* t_buf = p;  p += (size_t)ROWS*D;        // persistent
    float* q_buf = p;  p += (size_t)ROWS*D;        // persistent
    float* R     = p;  p += (size_t)ROWS*1024;     // phase-shared
    float* t2    = p;  p += (size_t)ROWS*D;

    float* qkv   = R;                              // ROWS*768   (phase 1)
    float* o_buf = R + (size_t)ROWS*768;           // ROWS*256   (phase 1)
    float* so_b  = R;                              // ROWS*256   (phase 2)
    float* aw_b  = R + (size_t)ROWS*256;           // ROWS*128   (phase 2)
    float* gates = R;                              // ROWS*512   (phase 3)
    float* hid   = R;                              // ROWS*1024  (phase 4)

    const size_t base_bytes = (size_t)((char*)p - (char*)d_ws);
    const size_t val_elems  = (size_t)BS*LEN_V*256;
    ushort_t* val_bf = (ushort_t*)p;
    const bool use_vbf = (ws_size >= base_bytes + val_elems*2);

    if (use_vbf)
        cvt_flat4<<<2048, 256, 0, stream>>>(value, val_bf, (int)(val_elems/4));
    prep0<<<ROWS, 256, 0, stream>>>(target, qpos, t_buf, q_buf);

    for (int i = 0; i < 6; ++i) {
        const float* Wqkv_i = Wqkv + (size_t)i*768*256;
        const float* bqkv_i = bqkv + (size_t)i*768;
        const float* Wo_i   = Wo   + (size_t)i*256*256;
        const float* bo_i   = bo   + (size_t)i*256;
        const float* n1g_i  = n1g  + (size_t)i*256;
        const float* n1b_i  = n1b  + (size_t)i*256;
        const float* soW_i  = soW  + (size_t)i*256*256;
        const float* sob_i  = sob  + (size_t)i*256;
        const float* awW_i  = awW  + (size_t)i*128*256;
        const float* awb_i  = awb  + (size_t)i*128;
        const float* gW_i   = gW   + (size_t)i*512*512;
        const float* gb_i   = gb   + (size_t)i*512;
        const float* gng_i  = gng  + (size_t)i*256;
        const float* gnb_i  = gnb  + (size_t)i*256;
        const float* l1W_i  = l1W  + (size_t)i*1024*256;
        const float* l1b_i  = l1b  + (size_t)i*1024;
        const float* l2W_i  = l2W  + (size_t)i*256*1024;
        const float* l2b_i  = l2b  + (size_t)i*256;
        const float* n3g_i  = n3g  + (size_t)i*256;
        const float* n3b_i  = n3b  + (size_t)i*256;

        // ---- MHA: merged QKV GEMM (bn<8: Q|K from q_buf; bn>=8: V from t_buf)
        gemm_f32<0><<<dim3(75, 12), 256, 0, stream>>>(
            q_buf, t_buf, 8, 256,  nullptr, 0, 0,
            Wqkv_i, nullptr, 999,  bqkv_i, nullptr,
            qkv, 768, nullptr, 0,  256);
        mha_block<<<BS*NH*4, 256, 0, stream>>>(qkv, o_buf);
        gemm_f32<0><<<dim3(75, 4), 256, 0, stream>>>(
            o_buf, o_buf, 999, 256,  nullptr, 0, 0,
            Wo_i, nullptr, 999,  bo_i, nullptr,
            t2, 256, nullptr, 0,  256);
        ln_res_pos<<<ROWS, 256, 0, stream>>>(t_buf, t2, n1g_i, n1b_i, qpos, t_buf, q_buf);

        // ---- deformable attention: merged so|aw GEMM (bn<4: so; bn>=4: aw)
        gemm_f32<0><<<dim3(75, 6), 256, 0, stream>>>(
            q_buf, q_buf, 999, 256,  nullptr, 0, 0,
            soW_i, awW_i, 4,  sob_i, awb_i,
            so_b, 256, aw_b, 128,  256);
        if (use_vbf)
            deform_attn<1><<<ROWS, 256, 0, stream>>>(val_bf, refp, so_b, aw_b, t2);
        else
            deform_attn<0><<<ROWS, 256, 0, stream>>>(value, refp, so_b, aw_b, t2);

        // ---- gating (concat fused via A2 k-split)
        gemm_f32<2><<<dim3(75, 8), 256, 0, stream>>>(
            t_buf, t_buf, 999, 256,  t2, 256, 256,
            gW_i, nullptr, 999,  gb_i, nullptr,
            gates, 512, nullptr, 0,  512);
        gate_ln<<<ROWS, 256, 0, stream>>>(t_buf, t2, gates, gng_i, gnb_i, t_buf);

        // ---- FFN
        gemm_f32<1><<<dim3(75, 16), 256, 0, stream>>>(
            t_buf, t_buf, 999, 256,  nullptr, 0, 0,
            l1W_i, nullptr, 999,  l1b_i, nullptr,
            hid, 1024, nullptr, 0,  256);
        gemm_f32<0><<<dim3(75, 4), 256, 0, stream>>>(
            hid, hid, 999, 1024,  nullptr, 0, 0,
            l2W_i, nullptr, 999,  l2b_i, nullptr,
            t2, 256, nullptr, 0,  1024);
        ln_clip<<<ROWS, 256, 0, stream>>>(t_buf, t2, n3g_i, n3b_i, qpos,
                                          (i == 5) ? (float*)d_out : t_buf,
                                          (i < 5) ? q_buf : nullptr);
    }
}

// Round 9
// 1307.348 us; speedup vs baseline: 1.0894x; 1.0213x over previous
//
#include <hip/hip_runtime.h>

#define BS 16
#define LQ 300
#define D 256
#define NH 8
#define HD 32
#define DFF 1024
#define ROWS (BS*LQ)    // 4800
#define LEN_V 8500

typedef __attribute__((ext_vector_type(8))) short short8;
typedef __attribute__((ext_vector_type(4))) float f32x4;

// bf16 round-to-nearest-even (low 16 bits)
__device__ __forceinline__ uint32_t bf16r(float x)
{
    const uint32_t u = __float_as_uint(x);
    return (u + 0x7fffu + ((u >> 16) & 1u)) >> 16;
}
__device__ __forceinline__ float lof(uint32_t p) { return __uint_as_float(p << 16); }
__device__ __forceinline__ float hif(uint32_t p) { return __uint_as_float(p & 0xffff0000u); }

// ---------------------------------------------------------------------------
// MFMA GEMM — EXACT R6 version (tile 64x64, BK=64, proven staging).
// Per-bn selects (all wave-uniform, resolved once at entry):
//   A-select:  bn >= bnsplit_a -> Aalt           (merged QKV)
//   W/C-select: bn >= bnw -> W2/bias2/C2/ldc2    (merged so|aw)
//   k-concat:  A2 != null && kg >= ksplit -> A2  (gates [t|t2] fusion)
// ACT: 0=none 1=relu 2=sigmoid
// ---------------------------------------------------------------------------
template<int ACT>
__global__ __launch_bounds__(256)
void gemm_f32(const float* __restrict__ A, const float* __restrict__ Aalt,
              int bnsplit_a, int lda,
              const float* __restrict__ A2, int lda2, int ksplit,
              const float* __restrict__ W, const float* __restrict__ W2, int bnw,
              const float* __restrict__ bias, const float* __restrict__ bias2,
              float* __restrict__ C, int ldc, float* __restrict__ C2, int ldc2,
              int K)
{
    __shared__ __align__(16) unsigned short As[64*64];   // [row][slot^], 128B rows
    __shared__ __align__(16) unsigned short Bs[64*64];
    const int tid  = threadIdx.x;
    const int bm   = blockIdx.x, bn = blockIdx.y;
    const int lane = tid & 63;
    const int w    = tid >> 6;
    const int wm   = (w >> 1) * 32, wn = (w & 1) * 32;
    const int fr   = lane & 15;     // fragment row/col
    const int fq   = lane >> 4;     // k-quad

    const int srow = tid >> 2;      // staging row 0..63
    const int sg   = tid & 3;       // staging slot sub-index

    // wave-uniform selects
    if (bn >= bnsplit_a) A = Aalt;
    const float* Wb; const float* biasb; float* Cb; int ldcb; int colbase;
    if (bn < bnw) {
        Wb = W  + (size_t)bn*64*K;        biasb = bias;
        Cb = C;  ldcb = ldc;  colbase = bn*64;
    } else {
        Wb = W2 + (size_t)(bn-bnw)*64*K;  biasb = bias2;
        Cb = C2; ldcb = ldc2; colbase = (bn-bnw)*64;
    }

    f32x4 acc[2][2] = {};

    for (int k0 = 0; k0 < K; k0 += 64) {
        float4 a0[2], a1[2], w0[2], w1[2];
#pragma unroll
        for (int p = 0; p < 2; ++p) {
            const int slot = sg + 4*p;        // 0..7 (8 elems each)
            const int kg   = k0 + slot*8;
            const float* Asrc = (A2 != nullptr && kg >= ksplit)
                ? (A2 + (size_t)(bm*64 + srow)*lda2 + (kg - ksplit))
                : (A  + (size_t)(bm*64 + srow)*lda  + kg);
            a0[p] = *reinterpret_cast<const float4*>(Asrc);
            a1[p] = *reinterpret_cast<const float4*>(Asrc + 4);
            const float* Wsrc = Wb + (size_t)srow*K + kg;
            w0[p] = *reinterpret_cast<const float4*>(Wsrc);
            w1[p] = *reinterpret_cast<const float4*>(Wsrc + 4);
        }
        __syncthreads();
#pragma unroll
        for (int p = 0; p < 2; ++p) {
            const int slot = (sg + 4*p) ^ (srow & 7);
            uint32_t pk[4];
            pk[0] = bf16r(a0[p].x) | (bf16r(a0[p].y) << 16);
            pk[1] = bf16r(a0[p].z) | (bf16r(a0[p].w) << 16);
            pk[2] = bf16r(a1[p].x) | (bf16r(a1[p].y) << 16);
            pk[3] = bf16r(a1[p].z) | (bf16r(a1[p].w) << 16);
            *reinterpret_cast<uint4*>(&As[srow*64 + slot*8]) =
                make_uint4(pk[0], pk[1], pk[2], pk[3]);
            pk[0] = bf16r(w0[p].x) | (bf16r(w0[p].y) << 16);
            pk[1] = bf16r(w0[p].z) | (bf16r(w0[p].w) << 16);
            pk[2] = bf16r(w1[p].x) | (bf16r(w1[p].y) << 16);
            pk[3] = bf16r(w1[p].z) | (bf16r(w1[p].w) << 16);
            *reinterpret_cast<uint4*>(&Bs[srow*64 + slot*8]) =
                make_uint4(pk[0], pk[1], pk[2], pk[3]);
        }
        __syncthreads();
#pragma unroll
        for (int ks = 0; ks < 2; ++ks) {
            short8 af[2], bf[2];
#pragma unroll
            for (int fm = 0; fm < 2; ++fm) {
                const int row = wm + fm*16 + fr;
                const int slot = (ks*4 + fq) ^ (row & 7);
                af[fm] = *reinterpret_cast<const short8*>(&As[row*64 + slot*8]);
            }
#pragma unroll
            for (int fn = 0; fn < 2; ++fn) {
                const int row = wn + fn*16 + fr;
                const int slot = (ks*4 + fq) ^ (row & 7);
                bf[fn] = *reinterpret_cast<const short8*>(&Bs[row*64 + slot*8]);
            }
#pragma unroll
            for (int fm = 0; fm < 2; ++fm)
#pragma unroll
                for (int fn = 0; fn < 2; ++fn)
                    acc[fm][fn] = __builtin_amdgcn_mfma_f32_16x16x32_bf16(
                        af[fm], bf[fn], acc[fm][fn], 0, 0, 0);
        }
    }

#pragma unroll
    for (int fm = 0; fm < 2; ++fm)
#pragma unroll
        for (int fn = 0; fn < 2; ++fn) {
            const int coll = wn + fn*16 + fr;
            const float bia = biasb[colbase + coll];
#pragma unroll
            for (int r = 0; r < 4; ++r) {
                const int row = bm*64 + wm + fm*16 + fq*4 + r;
                float v = acc[fm][fn][r] + bia;
                if (ACT == 1) v = fmaxf(v, 0.f);
                if (ACT == 2) v = 1.f / (1.f + __expf(-v));
                Cb[(size_t)row*ldcb + colbase + coll] = v;
            }
        }
}

// ---------------------------------------------------------------------------
// prep: t = target; q = target + pos
// ---------------------------------------------------------------------------
__global__ __launch_bounds__(256)
void prep0(const float* __restrict__ target, const float* __restrict__ pos,
           float* __restrict__ t, float* __restrict__ q)
{
    const size_t idx = (size_t)blockIdx.x*256 + threadIdx.x;
    const float v = target[idx];
    t[idx] = v;
    q[idx] = v + pos[idx];
}

// ---------------------------------------------------------------------------
// Fused MHA, keys-across-lanes. One block per (b,h,quarter).
// CHANGE vs R6: lane l scores keys 4l..4l+3 via ONE ds_read_b128 per d-pair
// (+ b32 tail for keys 256+l), replacing 5 scalar ds_read_b32 — QK phase was
// LDS-instruction-bound. Staging, softmax reduce, PV identical to R6.
// ---------------------------------------------------------------------------
__global__ __launch_bounds__(256)
void mha_block(const float* __restrict__ qkv, float* __restrict__ o)
{
    const int blk = blockIdx.x;          // ((b*8+h)*4 + quarter)
    const int quarter = blk & 3;
    const int bh = blk >> 2;
    const int b = bh >> 3, h = bh & 7;
    const int tid = threadIdx.x;
    const int lane = tid & 63;
    const int w = tid >> 6;

    __shared__ uint32_t Kp[16][320];     // [d-pair][key], pad 300..319 = 0
    __shared__ uint32_t Vp[150][32];     // [key-pair][d]
    __shared__ float    ws[4][304];      // per-wave softmax weights
    const float* base = qkv + (size_t)b * LQ * 768;
    const int hc = h * 32;

    for (int idx = tid; idx < 300*16; idx += 256) {
        const int j = idx >> 4, d2 = idx & 15;
        const float2 kv = *reinterpret_cast<const float2*>(base + (size_t)j*768 + 256 + hc + 2*d2);
        Kp[d2][j] = (bf16r(kv.y) << 16) | bf16r(kv.x);
    }
    for (int idx = tid; idx < 16*20; idx += 256)
        Kp[idx/20][300 + idx%20] = 0;
    for (int idx = tid; idx < 150*32; idx += 256) {
        const int jp = idx >> 5, d = idx & 31;
        const float lo = base[(size_t)(2*jp  )*768 + 512 + hc + d];
        const float hi = base[(size_t)(2*jp+1)*768 + 512 + hc + d];
        Vp[jp][d] = (bf16r(hi) << 16) | bf16r(lo);
    }
    __syncthreads();

    const float scale = 0.17677669529663687f;   // 1/sqrt(32)
    const int qbase = quarter * 75;
    for (int il = w; il < 75; il += 4) {
        const int iq = qbase + il;
        const float2* qrow = reinterpret_cast<const float2*>(base + (size_t)iq*768 + hc);

        // lane l: keys 4l..4l+3 (b128) + tail key 256+l (b32; pad-zero >=300)
        float s0=0.f, s1=0.f, s2=0.f, s3=0.f, s4=0.f;
#pragma unroll
        for (int d2 = 0; d2 < 16; ++d2) {
            const float2 q2 = qrow[d2];
            const uint4 kq = *reinterpret_cast<const uint4*>(&Kp[d2][4*lane]);
            s0 += lof(kq.x)*q2.x + hif(kq.x)*q2.y;
            s1 += lof(kq.y)*q2.x + hif(kq.y)*q2.y;
            s2 += lof(kq.z)*q2.x + hif(kq.z)*q2.y;
            s3 += lof(kq.w)*q2.x + hif(kq.w)*q2.y;
            const uint32_t kt = Kp[d2][256 + lane];
            s4 += lof(kt)*q2.x + hif(kt)*q2.y;
        }
        s0 *= scale; s1 *= scale; s2 *= scale; s3 *= scale;
        s4 = (lane < 44) ? s4*scale : -3e38f;

        float m = fmaxf(fmaxf(fmaxf(s0,s1), fmaxf(s2,s3)), s4);
#pragma unroll
        for (int off = 32; off; off >>= 1) m = fmaxf(m, __shfl_xor(m, off));
        const float e0 = __expf(s0-m), e1 = __expf(s1-m), e2 = __expf(s2-m), e3 = __expf(s3-m);
        const float e4 = (lane < 44) ? __expf(s4-m) : 0.f;
        float sum = e0+e1+e2+e3+e4;
#pragma unroll
        for (int off = 32; off; off >>= 1) sum += __shfl_xor(sum, off);
        const float inv = 1.f / sum;
        *reinterpret_cast<float4*>(&ws[w][4*lane]) = make_float4(e0, e1, e2, e3);
        if (lane < 44) ws[w][256 + lane] = e4;

        const int half = lane >> 5, d = lane & 31;
        float acc = 0.f;
#pragma unroll 5
        for (int jp = half*75; jp < half*75 + 75; ++jp) {
            const float2 w2 = *reinterpret_cast<const float2*>(&ws[w][2*jp]);
            const uint32_t v2 = Vp[jp][d];
            acc += lof(v2)*w2.x + hif(v2)*w2.y;
        }
        acc += __shfl_down(acc, 32);
        if (lane < 32)
            o[((size_t)(b*LQ + iq))*256 + hc + d] = acc * inv;
    }
}

// ---------------------------------------------------------------------------
__device__ __forceinline__ float blk_sum(float v, float* red)
{
#pragma unroll
    for (int off = 32; off; off >>= 1) v += __shfl_down(v, off, 64);
    const int lane = threadIdx.x & 63, w = threadIdx.x >> 6;
    if (lane == 0) red[w] = v;
    __syncthreads();
    const float s = red[0] + red[1] + red[2] + red[3];
    __syncthreads();
    return s;
}

// t_out = LN(t + t2) ; q_out = t_out + pos
__global__ __launch_bounds__(256)
void ln_res_pos(const float* __restrict__ t, const float* __restrict__ t2,
                const float* __restrict__ g, const float* __restrict__ bb,
                const float* __restrict__ pos,
                float* __restrict__ t_out, float* __restrict__ q_out)
{
    __shared__ float red[4];
    const size_t idx = (size_t)blockIdx.x*256 + threadIdx.x;
    const float x = t[idx] + t2[idx];
    const float mean = blk_sum(x, red) * (1.f/256.f);
    const float c = x - mean;
    const float var = blk_sum(c*c, red) * (1.f/256.f);
    const float y = c * rsqrtf(var + 1e-5f) * g[threadIdx.x] + bb[threadIdx.x];
    t_out[idx] = y;
    q_out[idx] = y + pos[idx];
}

// t_out = LN(g1*t + g2*t2)
__global__ __launch_bounds__(256)
void gate_ln(const float* __restrict__ t, const float* __restrict__ t2,
             const float* __restrict__ gates,
             const float* __restrict__ g, const float* __restrict__ bb,
             float* __restrict__ t_out)
{
    __shared__ float red[4];
    const int row = blockIdx.x, dd = threadIdx.x;
    const size_t idx = (size_t)row*256 + dd;
    const float g1 = gates[(size_t)row*512 + dd];
    const float g2 = gates[(size_t)row*512 + 256 + dd];
    const float x = g1 * t[idx] + g2 * t2[idx];
    const float mean = blk_sum(x, red) * (1.f/256.f);
    const float c = x - mean;
    const float var = blk_sum(c*c, red) * (1.f/256.f);
    t_out[idx] = c * rsqrtf(var + 1e-5f) * g[dd] + bb[dd];
}

// out = LN(clip(t + t2)) ; if q_out != null also q_out = out + pos
__global__ __launch_bounds__(256)
void ln_clip(const float* __restrict__ t, const float* __restrict__ t2,
             const float* __restrict__ g, const float* __restrict__ bb,
             const float* __restrict__ pos,
             float* __restrict__ outp, float* __restrict__ q_out)
{
    __shared__ float red[4];
    const size_t idx = (size_t)blockIdx.x*256 + threadIdx.x;
    float x = t[idx] + t2[idx];
    x = fminf(fmaxf(x, -65504.f), 65504.f);
    const float mean = blk_sum(x, red) * (1.f/256.f);
    const float c = x - mean;
    const float var = blk_sum(c*c, red) * (1.f/256.f);
    const float y = c * rsqrtf(var + 1e-5f) * g[threadIdx.x] + bb[threadIdx.x];
    outp[idx] = y;
    if (q_out != nullptr) q_out[idx] = y + pos[idx];
}

// ---------------------------------------------------------------------------
// MS-deformable attention gather with fused attention-weight softmax.
// so: [bq][256], awl: [bq][128] logits. One block per (b,q) = 8 heads x 32 d.
// ---------------------------------------------------------------------------
__global__ __launch_bounds__(256)
void deform_attn(const float* __restrict__ value, const float* __restrict__ refp,
                 const float* __restrict__ so, const float* __restrict__ awl,
                 float* __restrict__ outp)
{
    const int bq = blockIdx.x;
    const int b  = bq / LQ;
    const int tid = threadIdx.x;
    __shared__ int   s_idx[128][4];
    __shared__ float s_w[128][4];
    if (tid < 128) {
        const int hp = tid;
        const int p  = hp & 15;
        const int lvl = p >> 2;
        const float Wl = (lvl == 0) ? 80.f : (lvl == 1) ? 40.f : (lvl == 2) ? 20.f : 10.f;
        const float Hl = Wl;
        const int off  = (lvl == 0) ? 0 : (lvl == 1) ? 6400 : (lvl == 2) ? 8000 : 8400;
        // fused softmax over the 16 points of this head (16-lane groups)
        const float logit = awl[(size_t)bq*128 + hp];
        float m = logit;
#pragma unroll
        for (int o = 8; o; o >>= 1) m = fmaxf(m, __shfl_xor(m, o, 16));
        const float e = __expf(logit - m);
        float ssum = e;
#pragma unroll
        for (int o = 8; o; o >>= 1) ssum += __shfl_xor(ssum, o, 16);
        const float a = e / ssum;

        const float cx = refp[bq*4+0], cy = refp[bq*4+1];
        const float rw = refp[bq*4+2], rh = refp[bq*4+3];
        const float lx = cx + so[(size_t)bq*256 + hp*2    ] * rw * 0.125f;
        const float ly = cy + so[(size_t)bq*256 + hp*2 + 1] * rh * 0.125f;
        const float x = lx * Wl - 0.5f;
        const float y = ly * Hl - 0.5f;
        const float x0 = floorf(x), y0 = floorf(y);
        const float wx1 = x - x0, wx0 = 1.f - wx1;
        const float wy1 = y - y0, wy0 = 1.f - wy1;
        const float xs[2]  = {x0, x0 + 1.f}, ys[2]  = {y0, y0 + 1.f};
        const float wxs[2] = {wx0, wx1},     wys[2] = {wy0, wy1};
#pragma unroll
        for (int cyi = 0; cyi < 2; ++cyi)
#pragma unroll
            for (int cxi = 0; cxi < 2; ++cxi) {
                const float xi = xs[cxi], yi = ys[cyi];
                const bool valid = (xi >= 0.f) && (xi <= Wl - 1.f) &&
                                   (yi >= 0.f) && (yi <= Hl - 1.f);
                const float xc = fminf(fmaxf(xi, 0.f), Wl - 1.f);
                const float yc = fminf(fmaxf(yi, 0.f), Hl - 1.f);
                const int c = cyi*2 + cxi;
                s_idx[hp][c] = (int)(yc*Wl + xc) + off;
                s_w[hp][c]   = valid ? (wxs[cxi]*wys[cyi]*a) : 0.f;
            }
    }
    __syncthreads();
    const int h = tid >> 5, d = tid & 31;
    const int col = h*32 + d;
    const float* vb = value + (size_t)b * LEN_V * 256;
    float acc = 0.f;
#pragma unroll
    for (int p = 0; p < 16; ++p) {
        const int hp = (h << 4) | p;
#pragma unroll
        for (int c = 0; c < 4; ++c)
            acc += s_w[hp][c] * vb[(size_t)s_idx[hp][c]*256 + col];
    }
    outp[(size_t)bq*256 + col] = acc;
}

// ---------------------------------------------------------------------------
extern "C" void kernel_launch(void* const* d_in, const int* in_sizes, int n_in,
                              void* d_out, int out_size, void* d_ws, size_t ws_size,
                              hipStream_t stream)
{
    (void)in_sizes; (void)n_in; (void)out_size; (void)ws_size;
    const float* target = (const float*)d_in[0];
    const float* refp   = (const float*)d_in[1];
    const float* value  = (const float*)d_in[2];
    const float* qpos   = (const float*)d_in[3];
    const float* Wqkv   = (const float*)d_in[4];
    const float* bqkv   = (const float*)d_in[5];
    const float* Wo     = (const float*)d_in[6];
    const float* bo     = (const float*)d_in[7];
    const float* n1g    = (const float*)d_in[8];
    const float* n1b    = (const float*)d_in[9];
    const float* soW    = (const float*)d_in[10];
    const float* sob    = (const float*)d_in[11];
    const float* awW    = (const float*)d_in[12];
    const float* awb    = (const float*)d_in[13];
    const float* gW     = (const float*)d_in[14];
    const float* gb     = (const float*)d_in[15];
    const float* gng    = (const float*)d_in[16];
    const float* gnb    = (const float*)d_in[17];
    const float* l1W    = (const float*)d_in[18];
    const float* l1b    = (const float*)d_in[19];
    const float* l2W    = (const float*)d_in[20];
    const float* l2b    = (const float*)d_in[21];
    const float* n3g    = (const float*)d_in[22];
    const float* n3b    = (const float*)d_in[23];

    // ---- workspace carve; region R is time-shared: qkv|o -> so|aw -> gates -> hid
    float* p = (float*)d_ws;
    float* t_buf = p;  p += (size_t)ROWS*D;        // persistent
    float* q_buf = p;  p += (size_t)ROWS*D;        // persistent
    float* R     = p;  p += (size_t)ROWS*1024;     // phase-shared
    float* t2    = p;  p += (size_t)ROWS*D;

    float* qkv   = R;                              // ROWS*768   (phase 1)
    float* o_buf = R + (size_t)ROWS*768;           // ROWS*256   (phase 1)
    float* so_b  = R;                              // ROWS*256   (phase 2)
    float* aw_b  = R + (size_t)ROWS*256;           // ROWS*128   (phase 2)
    float* gates = R;                              // ROWS*512   (phase 3)
    float* hid   = R;                              // ROWS*1024  (phase 4)

    prep0<<<ROWS, 256, 0, stream>>>(target, qpos, t_buf, q_buf);

    for (int i = 0; i < 6; ++i) {
        const float* Wqkv_i = Wqkv + (size_t)i*768*256;
        const float* bqkv_i = bqkv + (size_t)i*768;
        const float* Wo_i   = Wo   + (size_t)i*256*256;
        const float* bo_i   = bo   + (size_t)i*256;
        const float* n1g_i  = n1g  + (size_t)i*256;
        const float* n1b_i  = n1b  + (size_t)i*256;
        const float* soW_i  = soW  + (size_t)i*256*256;
        const float* sob_i  = sob  + (size_t)i*256;
        const float* awW_i  = awW  + (size_t)i*128*256;
        const float* awb_i  = awb  + (size_t)i*128;
        const float* gW_i   = gW   + (size_t)i*512*512;
        const float* gb_i   = gb   + (size_t)i*512;
        const float* gng_i  = gng  + (size_t)i*256;
        const float* gnb_i  = gnb  + (size_t)i*256;
        const float* l1W_i  = l1W  + (size_t)i*1024*256;
        const float* l1b_i  = l1b  + (size_t)i*1024;
        const float* l2W_i  = l2W  + (size_t)i*256*1024;
        const float* l2b_i  = l2b  + (size_t)i*256;
        const float* n3g_i  = n3g  + (size_t)i*256;
        const float* n3b_i  = n3b  + (size_t)i*256;

        // ---- MHA: merged QKV GEMM (bn<8: Q|K from q_buf; bn>=8: V from t_buf)
        gemm_f32<0><<<dim3(75, 12), 256, 0, stream>>>(
            q_buf, t_buf, 8, 256,  nullptr, 0, 0,
            Wqkv_i, nullptr, 999,  bqkv_i, nullptr,
            qkv, 768, nullptr, 0,  256);
        mha_block<<<BS*NH*4, 256, 0, stream>>>(qkv, o_buf);
        gemm_f32<0><<<dim3(75, 4), 256, 0, stream>>>(
            o_buf, o_buf, 999, 256,  nullptr, 0, 0,
            Wo_i, nullptr, 999,  bo_i, nullptr,
            t2, 256, nullptr, 0,  256);
        ln_res_pos<<<ROWS, 256, 0, stream>>>(t_buf, t2, n1g_i, n1b_i, qpos, t_buf, q_buf);

        // ---- deformable attention: merged so|aw GEMM (bn<4: so; bn>=4: aw)
        gemm_f32<0><<<dim3(75, 6), 256, 0, stream>>>(
            q_buf, q_buf, 999, 256,  nullptr, 0, 0,
            soW_i, awW_i, 4,  sob_i, awb_i,
            so_b, 256, aw_b, 128,  256);
        deform_attn<<<ROWS, 256, 0, stream>>>(value, refp, so_b, aw_b, t2);

        // ---- gating (concat fused via A2 k-split)
        gemm_f32<2><<<dim3(75, 8), 256, 0, stream>>>(
            t_buf, t_buf, 999, 256,  t2, 256, 256,
            gW_i, nullptr, 999,  gb_i, nullptr,
            gates, 512, nullptr, 0,  512);
        gate_ln<<<ROWS, 256, 0, stream>>>(t_buf, t2, gates, gng_i, gnb_i, t_buf);

        // ---- FFN
        gemm_f32<1><<<dim3(75, 16), 256, 0, stream>>>(
            t_buf, t_buf, 999, 256,  nullptr, 0, 0,
            l1W_i, nullptr, 999,  l1b_i, nullptr,
            hid, 1024, nullptr, 0,  256);
        gemm_f32<0><<<dim3(75, 4), 256, 0, stream>>>(
            hid, hid, 999, 1024,  nullptr, 0, 0,
            l2W_i, nullptr, 999,  l2b_i, nullptr,
            t2, 256, nullptr, 0,  1024);
        ln_clip<<<ROWS, 256, 0, stream>>>(t_buf, t2, n3g_i, n3b_i, qpos,
                                          (i == 5) ? (float*)d_out : t_buf,
                                          (i < 5) ? q_buf : nullptr);
    }
}